// Round 7
// baseline (164.033 us; speedup 1.0000x reference)
//
#include <hip/hip_runtime.h>

#define E_DIM 1024
#define NHEAD 16
#define HDIM 64
#define SEQ 2048
#define NBATCH 2
#define WIN 256
#define MTOK (NBATCH * SEQ) // 4096
#define BKT 32              // K per pipeline tile
#define NT (E_DIM / BKT)    // 32 tiles

typedef __attribute__((ext_vector_type(4))) float f32x4;
typedef __attribute__((ext_vector_type(8))) short short8;
typedef __attribute__((ext_vector_type(4))) unsigned short u16x4;

#define AS1 __attribute__((address_space(1)))
#define AS3 __attribute__((address_space(3)))

__device__ __forceinline__ void gll16(const void* g, void* l) {
    __builtin_amdgcn_global_load_lds((const AS1 void*)g, (AS3 void*)l, 16, 0, 0);
}

__device__ __forceinline__ unsigned short f2bf(float f) {
    union { float f; unsigned u; } a; a.f = f;
    unsigned r = a.u + 0x7fffu + ((a.u >> 16) & 1u);
    return (unsigned short)(r >> 16);
}

// ---------------- fused fp32 -> bf16 conversion: x (4 segs) + 4 weights ----------------
__global__ __launch_bounds__(256) void conv_all(const float* __restrict__ x,
        const float* __restrict__ w0, const float* __restrict__ w1,
        const float* __restrict__ w2, const float* __restrict__ w3,
        unsigned short* __restrict__ xo,
        unsigned short* __restrict__ o0, unsigned short* __restrict__ o1,
        unsigned short* __restrict__ o2, unsigned short* __restrict__ o3) {
    const int seg = blockIdx.y;   // 0..3: x quarters; 4..7: weights
    const float* src;
    unsigned short* dst;
    if (seg < 4) { src = x + (size_t)seg * 1048576; dst = xo + (size_t)seg * 1048576; }
    else {
        src = (seg == 4) ? w0 : (seg == 5) ? w1 : (seg == 6) ? w2 : w3;
        dst = (seg == 4) ? o0 : (seg == 5) ? o1 : (seg == 6) ? o2 : o3;
    }
    int i = blockIdx.x * 256 + threadIdx.x;
    float4 v = ((const float4*)src)[i];
    u16x4 o;
    o[0] = f2bf(v.x); o[1] = f2bf(v.y); o[2] = f2bf(v.z); o[3] = f2bf(v.w);
    ((u16x4*)dst)[i] = o;
}

// ---------------- QKV GEMM: 2-phase per tile, 4-deep LDS pipeline, ledger-verified ----------------
// Prologue: STAGE(0),STAGE(1); vmcnt(4); BAR            -> tile0 landed for ALL waves
// Tile t: P0{read slot t; STAGE_A(t+2); BAR; lgkm0; 16 MFMA}
//         P1{read slot t; STAGE_B(t+2); BAR; lgkm0; 16 MFMA; vmcnt(4|0); BAR}
// The P1-tail vmcnt+BAR guarantees tile t+1's staging landed for all waves before
// the next tile's reads (round-6 bug: reads raced ahead of other waves' staging).
__global__ __launch_bounds__(512, 2) void gemm8_qkv(const unsigned short* __restrict__ xb,
        const unsigned short* __restrict__ wqb, const unsigned short* __restrict__ wkb,
        const unsigned short* __restrict__ wvb,
        const float* __restrict__ bq, const float* __restrict__ bk, const float* __restrict__ bv,
        unsigned short* __restrict__ qo, unsigned short* __restrict__ ko,
        unsigned short* __restrict__ vTo) {
    __shared__ char lds[131072];
    const int tid = threadIdx.x;
    const int w = tid >> 6, l = tid & 63;
    const int r16 = l & 15, kq = l >> 4;
    const int wm = w >> 2, wn = w & 3;
    const int m0 = blockIdx.x * 256;
    const int by = blockIdx.y;            // 0..11
    const int mat = by >> 2;              // 0:Q 1:K 2:V
    const int nb = (by & 3) * 256;
    const unsigned short* Bw = (mat == 0) ? wqb : (mat == 1) ? wkb : wvb;

    const int srow = tid >> 2;
    const int sslot = tid & 3;
    const int fsw = (srow >> 1) & 3;
    const int gslot = (sslot ^ fsw) * 8;
    const unsigned short* aSrc0 = xb + (size_t)(m0 + srow) * E_DIM + gslot;
    const unsigned short* aSrc1 = aSrc0 + (size_t)128 * E_DIM;
    const unsigned short* bSrc0 = Bw + (size_t)(nb + srow) * E_DIM + gslot;
    const unsigned short* bSrc1 = bSrc0 + (size_t)128 * E_DIM;
    const int dstOff = w * 1024;

#define STAGE_A(t) { char* d_ = lds + ((t) & 3) * 32768 + dstOff; \
                     gll16(aSrc0 + (t) * BKT, d_); gll16(aSrc1 + (t) * BKT, d_ + 8192); }
#define STAGE_B(t) { char* d_ = lds + ((t) & 3) * 32768 + 16384 + dstOff; \
                     gll16(bSrc0 + (t) * BKT, d_); gll16(bSrc1 + (t) * BKT, d_ + 8192); }

    f32x4 acc[8][4];
    #pragma unroll
    for (int m = 0; m < 8; ++m)
        #pragma unroll
        for (int n = 0; n < 4; ++n)
            acc[m][n] = (f32x4){0.f, 0.f, 0.f, 0.f};

    STAGE_A(0); STAGE_B(0); STAGE_A(1); STAGE_B(1);
    asm volatile("s_waitcnt vmcnt(4)" ::: "memory");   // my tile-0 loads landed
    __builtin_amdgcn_sched_barrier(0);
    __builtin_amdgcn_s_barrier();                      // everyone's tile-0 loads landed

    const int fs = (r16 >> 1) & 3;
    const int rdoff = (kq ^ fs) * 16;

    for (int t = 0; t < NT; ++t) {
        char* la = lds + (t & 3) * 32768;
        char* lb = la + 16384;
        // ---- phase 0: B[0..3] + A[0..3] reads, stage A(t+2), bar, lgkm0, 16 MFMA ----
        short8 bfr[4], af[4];
        #pragma unroll
        for (int n = 0; n < 4; ++n)
            bfr[n] = *(const short8*)(lb + (wn * 64 + n * 16 + r16) * 64 + rdoff);
        #pragma unroll
        for (int j = 0; j < 4; ++j)
            af[j] = *(const short8*)(la + (wm * 128 + j * 16 + r16) * 64 + rdoff);
        if (t + 2 < NT) STAGE_A(t + 2);
        __builtin_amdgcn_s_barrier();
        asm volatile("s_waitcnt lgkmcnt(0)" ::: "memory");
        __builtin_amdgcn_sched_barrier(0);
        __builtin_amdgcn_s_setprio(1);
        #pragma unroll
        for (int j = 0; j < 4; ++j)
            #pragma unroll
            for (int n = 0; n < 4; ++n)
                acc[j][n] = __builtin_amdgcn_mfma_f32_16x16x32_bf16(af[j], bfr[n], acc[j][n], 0, 0, 0);
        __builtin_amdgcn_s_setprio(0);
        // ---- phase 1: A[4..7] reads, stage B(t+2), bar, lgkm0, 16 MFMA ----
        short8 af2[4];
        #pragma unroll
        for (int j = 0; j < 4; ++j)
            af2[j] = *(const short8*)(la + (wm * 128 + (4 + j) * 16 + r16) * 64 + rdoff);
        if (t + 2 < NT) STAGE_B(t + 2);
        __builtin_amdgcn_s_barrier();
        asm volatile("s_waitcnt lgkmcnt(0)" ::: "memory");
        __builtin_amdgcn_sched_barrier(0);
        __builtin_amdgcn_s_setprio(1);
        #pragma unroll
        for (int j = 0; j < 4; ++j)
            #pragma unroll
            for (int n = 0; n < 4; ++n)
                acc[4 + j][n] = __builtin_amdgcn_mfma_f32_16x16x32_bf16(af2[j], bfr[n], acc[4 + j][n], 0, 0, 0);
        __builtin_amdgcn_s_setprio(0);
        // ---- tile tail: make tile t+1's staging visible to ALL waves ----
        if (t < NT - 1) {
            // in-flight: tile t+1 (4 loads) + tile t+2 (4 if staged this tile)
            if (t < NT - 2) { asm volatile("s_waitcnt vmcnt(4)" ::: "memory"); }
            else            { asm volatile("s_waitcnt vmcnt(0)" ::: "memory"); }
            __builtin_amdgcn_sched_barrier(0);
            __builtin_amdgcn_s_barrier();
        }
    }
#undef STAGE_A
#undef STAGE_B

    const float* bias = (mat == 0) ? bq : (mat == 1) ? bk : bv;
    const float scale = (mat == 0) ? 0.125f : 1.0f;   // D^-0.5 folded into Q
    #pragma unroll
    for (int n = 0; n < 4; ++n) {
        int e = nb + wn * 64 + n * 16 + r16;
        float bb = bias[e];
        int h = e >> 6, d = e & 63;
        #pragma unroll
        for (int m = 0; m < 8; ++m) {
            int tok = m0 + wm * 128 + m * 16 + kq * 4;
            int b = tok >> 11, s = tok & (SEQ - 1);
            if (mat == 2) {
                u16x4 o;
                #pragma unroll
                for (int r = 0; r < 4; ++r) o[r] = f2bf(acc[m][n][r] + bb);
                *(u16x4*)(vTo + ((size_t)(b * NHEAD + h) * HDIM + d) * SEQ + s) = o;
            } else {
                unsigned short* dst = (mat == 0) ? qo : ko;
                #pragma unroll
                for (int r = 0; r < 4; ++r) {
                    float val = (acc[m][n][r] + bb) * scale;
                    dst[((size_t)(b * NHEAD + h) * SEQ + s + r) * HDIM + d] = f2bf(val);
                }
            }
        }
    }
}

// ---------------- output projection: 128x128, 4 waves, 1 phase/tile, same ledger ----------------
__global__ __launch_bounds__(256, 2) void gemm_out(const unsigned short* __restrict__ yb,
        const unsigned short* __restrict__ wob, const float* __restrict__ bo,
        float* __restrict__ out) {
    __shared__ char lds[65536];
    const int tid = threadIdx.x;
    const int w = tid >> 6, l = tid & 63;
    const int r16 = l & 15, kq = l >> 4;
    const int wr = w >> 1, wc = w & 1;
    const int m0 = blockIdx.x * 128;
    const int n0 = blockIdx.y * 128;

    const int srow = tid >> 2;
    const int sslot = tid & 3;
    const int fsw = (srow >> 1) & 3;
    const int gslot = (sslot ^ fsw) * 8;
    const unsigned short* aSrc0 = yb + (size_t)(m0 + srow) * E_DIM + gslot;
    const unsigned short* aSrc1 = aSrc0 + (size_t)64 * E_DIM;
    const unsigned short* bSrc0 = wob + (size_t)(n0 + srow) * E_DIM + gslot;
    const unsigned short* bSrc1 = bSrc0 + (size_t)64 * E_DIM;
    const int dstOff = w * 1024;

#define STAGE_A(t) { char* d_ = lds + ((t) & 3) * 16384 + dstOff; \
                     gll16(aSrc0 + (t) * BKT, d_); gll16(aSrc1 + (t) * BKT, d_ + 4096); }
#define STAGE_B(t) { char* d_ = lds + ((t) & 3) * 16384 + 8192 + dstOff; \
                     gll16(bSrc0 + (t) * BKT, d_); gll16(bSrc1 + (t) * BKT, d_ + 4096); }

    f32x4 acc[4][4];
    #pragma unroll
    for (int m = 0; m < 4; ++m)
        #pragma unroll
        for (int n = 0; n < 4; ++n)
            acc[m][n] = (f32x4){0.f, 0.f, 0.f, 0.f};

    STAGE_A(0); STAGE_B(0); STAGE_A(1); STAGE_B(1);
    asm volatile("s_waitcnt vmcnt(4)" ::: "memory");
    __builtin_amdgcn_sched_barrier(0);
    __builtin_amdgcn_s_barrier();

    const int fs = (r16 >> 1) & 3;
    const int rdoff = (kq ^ fs) * 16;

    for (int t = 0; t < NT; ++t) {
        char* la = lds + (t & 3) * 16384;
        char* lb = la + 8192;
        short8 bfr[4], af[4];
        #pragma unroll
        for (int n = 0; n < 4; ++n)
            bfr[n] = *(const short8*)(lb + (wc * 64 + n * 16 + r16) * 64 + rdoff);
        #pragma unroll
        for (int m = 0; m < 4; ++m)
            af[m] = *(const short8*)(la + (wr * 64 + m * 16 + r16) * 64 + rdoff);
        if (t + 2 < NT) { STAGE_A(t + 2); STAGE_B(t + 2); }
        __builtin_amdgcn_s_barrier();
        asm volatile("s_waitcnt lgkmcnt(0)" ::: "memory");
        __builtin_amdgcn_sched_barrier(0);
        __builtin_amdgcn_s_setprio(1);
        #pragma unroll
        for (int m = 0; m < 4; ++m)
            #pragma unroll
            for (int n = 0; n < 4; ++n)
                acc[m][n] = __builtin_amdgcn_mfma_f32_16x16x32_bf16(af[m], bfr[n], acc[m][n], 0, 0, 0);
        __builtin_amdgcn_s_setprio(0);
        if (t < NT - 1) {
            if (t < NT - 2) { asm volatile("s_waitcnt vmcnt(4)" ::: "memory"); }
            else            { asm volatile("s_waitcnt vmcnt(0)" ::: "memory"); }
            __builtin_amdgcn_sched_barrier(0);
            __builtin_amdgcn_s_barrier();
        }
    }
#undef STAGE_A
#undef STAGE_B

    #pragma unroll
    for (int n = 0; n < 4; ++n) {
        int e = n0 + wc * 64 + n * 16 + r16;
        float bb = bo[e];
        #pragma unroll
        for (int m = 0; m < 4; ++m) {
            #pragma unroll
            for (int r = 0; r < 4; ++r) {
                int tok = m0 + wr * 64 + m * 16 + kq * 4 + r;
                out[(size_t)tok * E_DIM + e] = acc[m][n][r] + bb;
            }
        }
    }
}

// ---------------- sliding-window flash attention: 32 q-rows per wave ----------------
// MODE: 0 = interior (no mask), 1 = head tile (key < qrow-WIN masked), 2 = tail (key > qrow masked)
template<int MODE, bool PRE>
__device__ __forceinline__ void attn_tile(int k0,
        const unsigned short* __restrict__ kp, const unsigned short* __restrict__ vp,
        int r16, int kq, char* pl,
        const short8 (&qf)[2][2], short8 (&kf)[2][2],
        f32x4 (&po)[2][4], float (&mrow)[2][4], float (&lsum)[2][4]) {
    f32x4 sc[2][2];
    #pragma unroll
    for (int mf = 0; mf < 2; ++mf)
        #pragma unroll
        for (int n = 0; n < 2; ++n) {
            f32x4 z = {0.f, 0.f, 0.f, 0.f};
            z = __builtin_amdgcn_mfma_f32_16x16x32_bf16(qf[mf][0], kf[n][0], z, 0, 0, 0);
            sc[mf][n] = __builtin_amdgcn_mfma_f32_16x16x32_bf16(qf[mf][1], kf[n][1], z, 0, 0, 0);
        }
    if (PRE) {
        #pragma unroll
        for (int n = 0; n < 2; ++n) {
            const unsigned short* kr = kp + (size_t)(k0 + 32 + n * 16 + r16) * HDIM + kq * 8;
            kf[n][0] = *(const short8*)(kr);
            kf[n][1] = *(const short8*)(kr + 32);
        }
    }
    short8 vf[4];
    #pragma unroll
    for (int nn = 0; nn < 4; ++nn)
        vf[nn] = *(const short8*)(vp + (size_t)(nn * 16 + r16) * SEQ + k0 + kq * 8);

    float tmax[2][4];
    #pragma unroll
    for (int mf = 0; mf < 2; ++mf)
        #pragma unroll
        for (int r = 0; r < 4; ++r) {
            int rel = mf * 16 + kq * 4 + r;
            if (MODE == 1) {
                if (r16 < rel)      sc[mf][0][r] = -1e30f;
                if (16 + r16 < rel) sc[mf][1][r] = -1e30f;
            }
            if (MODE == 2) {
                if (r16 > rel)      sc[mf][0][r] = -1e30f;
                if (16 + r16 > rel) sc[mf][1][r] = -1e30f;
            }
            tmax[mf][r] = fmaxf(sc[mf][0][r], sc[mf][1][r]);
        }
    #pragma unroll
    for (int off = 1; off < 16; off <<= 1)
        #pragma unroll
        for (int mf = 0; mf < 2; ++mf)
            #pragma unroll
            for (int r = 0; r < 4; ++r)
                tmax[mf][r] = fmaxf(tmax[mf][r], __shfl_xor(tmax[mf][r], off));
    float pv[2][2][4];
    #pragma unroll
    for (int mf = 0; mf < 2; ++mf)
        #pragma unroll
        for (int r = 0; r < 4; ++r) {
            float mnew = fmaxf(mrow[mf][r], tmax[mf][r]);
            float resc = __expf(mrow[mf][r] - mnew);
            mrow[mf][r] = mnew;
            float p0 = __expf(sc[mf][0][r] - mnew);
            float p1 = __expf(sc[mf][1][r] - mnew);
            lsum[mf][r] = lsum[mf][r] * resc + p0 + p1;
            po[mf][0][r] *= resc; po[mf][1][r] *= resc;
            po[mf][2][r] *= resc; po[mf][3][r] *= resc;
            pv[mf][0][r] = p0; pv[mf][1][r] = p1;
        }
    #pragma unroll
    for (int mf = 0; mf < 2; ++mf)
        #pragma unroll
        for (int r = 0; r < 4; ++r) {
            int row = kq * 4 + r;
            int c0 = r16 ^ ((row & 7) << 3);
            int c1 = c0 ^ 16;
            *(unsigned short*)(pl + mf * 2048 + row * 128 + c0 * 2) = f2bf(pv[mf][0][r]);
            *(unsigned short*)(pl + mf * 2048 + row * 128 + c1 * 2) = f2bf(pv[mf][1][r]);
        }
    short8 pa[2];
    #pragma unroll
    for (int mf = 0; mf < 2; ++mf)
        pa[mf] = *(const short8*)(pl + mf * 2048 + r16 * 128 + ((kq ^ (r16 & 7)) * 16));
    #pragma unroll
    for (int nn = 0; nn < 4; ++nn) {
        po[0][nn] = __builtin_amdgcn_mfma_f32_16x16x32_bf16(pa[0], vf[nn], po[0][nn], 0, 0, 0);
        po[1][nn] = __builtin_amdgcn_mfma_f32_16x16x32_bf16(pa[1], vf[nn], po[1][nn], 0, 0, 0);
    }
}

__global__ __launch_bounds__(256) void attn_swa(const unsigned short* __restrict__ q,
                                                const unsigned short* __restrict__ k,
                                                const unsigned short* __restrict__ vT,
                                                unsigned short* __restrict__ y) {
    __shared__ char plds[4 * 4096];
    const int t = threadIdx.x;
    const int w = t >> 6, l = t & 63;
    const int r16 = l & 15, kq = l >> 4;
    const int wid = blockIdx.x * 4 + w;
    const int bh = wid >> 6;
    const int q0 = (wid & 63) * 32;
    const unsigned short* qp = q + (size_t)bh * SEQ * HDIM;
    const unsigned short* kp = k + (size_t)bh * SEQ * HDIM;
    const unsigned short* vp = vT + (size_t)bh * HDIM * SEQ;
    char* pl = plds + w * 4096;

    short8 qf[2][2];
    #pragma unroll
    for (int mf = 0; mf < 2; ++mf) {
        const unsigned short* qr = qp + (q0 + mf * 16 + r16) * HDIM + kq * 8;
        qf[mf][0] = *(const short8*)(qr);
        qf[mf][1] = *(const short8*)(qr + 32);
    }

    f32x4 po[2][4];
    float mrow[2][4], lsum[2][4];
    #pragma unroll
    for (int mf = 0; mf < 2; ++mf) {
        #pragma unroll
        for (int nn = 0; nn < 4; ++nn) po[mf][nn] = (f32x4){0.f, 0.f, 0.f, 0.f};
        #pragma unroll
        for (int r = 0; r < 4; ++r) { mrow[mf][r] = -1e30f; lsum[mf][r] = 0.f; }
    }

    const int kstart = (q0 >= WIN) ? (q0 - WIN) : 0;
    short8 kf[2][2];
    #pragma unroll
    for (int n = 0; n < 2; ++n) {
        const unsigned short* kr = kp + (size_t)(kstart + n * 16 + r16) * HDIM + kq * 8;
        kf[n][0] = *(const short8*)(kr);
        kf[n][1] = *(const short8*)(kr + 32);
    }

    int k0 = kstart;
    if (q0 >= WIN) {
        attn_tile<1, true>(k0, kp, vp, r16, kq, pl, qf, kf, po, mrow, lsum);
        k0 += 32;
    }
    for (; k0 < q0; k0 += 32)
        attn_tile<0, true>(k0, kp, vp, r16, kq, pl, qf, kf, po, mrow, lsum);
    attn_tile<2, false>(q0, kp, vp, r16, kq, pl, qf, kf, po, mrow, lsum);

    #pragma unroll
    for (int off = 1; off < 16; off <<= 1)
        #pragma unroll
        for (int mf = 0; mf < 2; ++mf)
            #pragma unroll
            for (int r = 0; r < 4; ++r)
                lsum[mf][r] += __shfl_xor(lsum[mf][r], off);

    const int b = bh >> 4, h = bh & 15;
    #pragma unroll
    for (int mf = 0; mf < 2; ++mf)
        #pragma unroll
        for (int nn = 0; nn < 4; ++nn)
            #pragma unroll
            for (int r = 0; r < 4; ++r) {
                int s = q0 + mf * 16 + kq * 4 + r;
                float val = po[mf][nn][r] / lsum[mf][r];
                y[((size_t)(b * SEQ + s)) * E_DIM + h * HDIM + nn * 16 + r16] = f2bf(val);
            }
}

extern "C" void kernel_launch(void* const* d_in, const int* in_sizes, int n_in,
                              void* d_out, int out_size, void* d_ws, size_t ws_size,
                              hipStream_t stream) {
    const float* x  = (const float*)d_in[0];
    const float* Wq = (const float*)d_in[1];
    const float* Wk = (const float*)d_in[2];
    const float* Wv = (const float*)d_in[3];
    const float* Wo = (const float*)d_in[4];
    const float* bq = (const float*)d_in[5];
    const float* bk = (const float*)d_in[6];
    const float* bv = (const float*)d_in[7];
    const float* bo = (const float*)d_in[8];
    float* out = (float*)d_out;

    char* ws = (char*)d_ws;
    unsigned short* xb  = (unsigned short*)(ws);                        // 8 MB
    unsigned short* wqb = (unsigned short*)(ws + ((size_t)8 << 20));    // 2 MB
    unsigned short* wkb = (unsigned short*)(ws + ((size_t)10 << 20));   // 2 MB
    unsigned short* wvb = (unsigned short*)(ws + ((size_t)12 << 20));   // 2 MB
    unsigned short* wob = (unsigned short*)(ws + ((size_t)14 << 20));   // 2 MB
    unsigned short* qw  = (unsigned short*)(ws + ((size_t)16 << 20));   // 8 MB
    unsigned short* kw  = (unsigned short*)(ws + ((size_t)24 << 20));   // 8 MB
    unsigned short* vTw = (unsigned short*)(ws + ((size_t)40 << 20));   // 8 MB
    unsigned short* yw  = (unsigned short*)(ws + ((size_t)48 << 20));   // 8 MB

    conv_all<<<dim3(1024, 8), 256, 0, stream>>>(x, Wq, Wk, Wv, Wo, xb, wqb, wkb, wvb, wob);

    gemm8_qkv<<<dim3(16, 12), 512, 0, stream>>>(xb, wqb, wkb, wvb, bq, bk, bv, qw, kw, vTw);
    attn_swa<<<512, 256, 0, stream>>>(qw, kw, vTw, yw);
    gemm_out<<<dim3(32, 8), 256, 0, stream>>>(yw, wob, bo, out);
}